// Round 1
// baseline (229.689 us; speedup 1.0000x reference)
//
#include <hip/hip_runtime.h>

#define B_ROWS 4096
#define N_CLUST 1024
#define KDIM 4096
#define NKT 32          // k-tiles of 128 halfs

#define EMA_OLD 0.01f
#define EMA_NEW 0.99f
#define MARGIN 2.0f     // screen d2 error max ~0.27 (40 sigma headroom)

typedef unsigned short ushortT;
typedef _Float16 half8 __attribute__((ext_vector_type(8)));
typedef float f32x16 __attribute__((ext_vector_type(16)));

// ---------------- workspace layout (bytes) ----------------
#define WS_WINNER_OFF 0                  // i32[1024], memset 0xFF
#define WS_Z_OFF      4096               // i32[4096]
#define WS_YY_OFF     20480              // f32[4096]
#define WS_MM_OFF     36864              // f32[1024]
#define WS_D2_OFF     65536              // f32[4096*1024] = 16 MiB
#define WS_YHI_OFF    (WS_D2_OFF + 16777216)     // 33.5 MB
#define WS_MHI_OFF    (WS_YHI_OFF + 33554432)    // 8.4 MB
#define WS_END        (WS_MHI_OFF + 8388608)     // ~58.8 MB

// ---------------- fused f16-hi convert + row sum-of-squares ----------------
// Tiled layout: block (rb, kt) of 64 rows x 128 halfs contiguous (16 KB).
// Within a row (16 chunks of 16B), logical chunk c stored at p = c ^ (r&15).
// One 256-thread block per source row; 512 chunks/row, 2 per thread.
__global__ __launch_bounds__(256) void convert_sumsq(
    const float* __restrict__ ysrc, const float* __restrict__ msrc,
    ushortT* __restrict__ yhi, ushortT* __restrict__ mhi,
    float* __restrict__ yy, float* __restrict__ mm) {
    const int blk = blockIdx.x;
    const float* src;
    ushortT* hi;
    float* out;
    int row;
    if (blk < B_ROWS) {
        src = ysrc; hi = yhi; out = yy + blk; row = blk;
    } else {
        row = blk - B_ROWS;
        src = msrc; hi = mhi; out = mm + row;
    }
    const int r = row & 63, rb = row >> 6;
    const int t = threadIdx.x;
    float s = 0.f;
#pragma unroll
    for (int h = 0; h < 2; ++h) {
        int ci = h * 256 + t;        // physical chunk in row [0,512)
        int kt = ci >> 4, p = ci & 15;
        int c = p ^ (r & 15);
        const float* sp = src + ((size_t)row << 12) + kt * 128 + c * 8;
        float4 v0 = *(const float4*)sp;
        float4 v1 = *(const float4*)(sp + 4);
        float vv[8] = {v0.x, v0.y, v0.z, v0.w, v1.x, v1.y, v1.z, v1.w};
        half8 hv;
#pragma unroll
        for (int i = 0; i < 8; ++i) {
            hv[i] = (_Float16)vv[i];
            s += vv[i] * vv[i];
        }
        size_t off = (((size_t)rb * NKT + kt) * 64 + r) * 128 + p * 8;
        *(half8*)(hi + off) = hv;
    }
    for (int off = 32; off > 0; off >>= 1) s += __shfl_down(s, off, 64);
    __shared__ float red[4];
    if ((t & 63) == 0) red[t >> 6] = s;
    __syncthreads();
    if (t == 0) out[0] = red[0] + red[1] + red[2] + red[3];
}

// ---------------- screen GEMM: d2_screen = yy - 2*Yhi@Mhi^T + mm ----------
__device__ __forceinline__ void gload_lds16(const void* g, void* l) {
    __builtin_amdgcn_global_load_lds(
        (const __attribute__((address_space(1))) unsigned int*)g,
        (__attribute__((address_space(3))) unsigned int*)l, 16, 0, 0);
}

__device__ __forceinline__ half8 ldfrag(const ushortT* s, int r, int c) {
    int p = c ^ (r & 15);
    return *(const half8*)(s + r * 128 + p * 8);
}

// v2: 128x128 block tile, 4 waves each owning a 64x64 output (2x2 MFMA tiles).
// Per k16 step per wave: 4 ds_read_b128 + 4 MFMA -> LDS:MFMA pipe ratio 1:1
// (was 2:1 at per-wave 32x32, a hard 50% MfmaUtil cap).
// Double-buffered LDS (2 x 64 KB = 128 KB), raw s_barrier + counted
// s_waitcnt vmcnt(16): next tile's 16 global_load_lds per wave stay in
// flight across the barrier; their latency hides under 32 MFMAs (~1024 clk).
// Grid 256 = 1 block/CU (forced: M*N/1024 SIMDs = one 64x64 tile per SIMD).
// Accumulation order per 32x32 output tile is identical to v1 -> d2 bits
// unchanged -> downstream (rescreen/argmin) results identical.
__global__ __launch_bounds__(256, 1) void screen_gemm(
    const ushortT* __restrict__ Ah, const ushortT* __restrict__ Bh,
    const float* __restrict__ yy, const float* __restrict__ mm,
    float* __restrict__ d2ws) {
    __shared__ __align__(16) ushortT sA[2][2 * 64 * 128];   // 2 bufs x 32 KB
    __shared__ __align__(16) ushortT sB[2][2 * 64 * 128];   // 2 bufs x 32 KB

    const int t = threadIdx.x, w = t >> 6, l = t & 63;
    const int bx = blockIdx.x >> 3, by = blockIdx.x & 7;    // 32 x 8 tiles
    const int row0 = bx * 128, col0 = by * 128;
    const int wr = (w >> 1) * 64, wc = (w & 1) * 64;        // wave 64x64 tile
    const int m0 = l & 31, hsel = l >> 5;

    // Per-wave staging: 8 x 1KB chunks of A + 8 of B per k-tile (16 vmem ops).
    // Chunk ch in [0,32): source tile = ch>>4 (two 64-row tiles), seg = ch&15.
    // LDS layout = verbatim copy of the two 16 KB source tiles, back to back.
    const char* gAbase = (const char*)Ah + (size_t)l * 16;
    const char* gBbase = (const char*)Bh + (size_t)l * 16;

    f32x16 acc[2][2];
#pragma unroll
    for (int i = 0; i < 2; ++i)
#pragma unroll
        for (int j = 0; j < 2; ++j)
#pragma unroll
            for (int r = 0; r < 16; ++r) acc[i][j][r] = 0.f;

#define STAGE(buf, kt)                                                        \
    {                                                                         \
        _Pragma("unroll")                                                     \
        for (int j = 0; j < 8; ++j) {                                         \
            int ch = w * 8 + j;                                               \
            int tile = ch >> 4, seg = ch & 15;                                \
            size_t go = ((size_t)((2 * bx + tile) * NKT + (kt)) << 14) +      \
                        seg * 1024;                                           \
            gload_lds16(gAbase + go,                                          \
                        (char*)&sA[buf][0] + tile * 16384 + seg * 1024);      \
            size_t gob = ((size_t)((2 * by + tile) * NKT + (kt)) << 14) +     \
                         seg * 1024;                                          \
            gload_lds16(gBbase + gob,                                         \
                        (char*)&sB[buf][0] + tile * 16384 + seg * 1024);      \
        }                                                                     \
    }

    STAGE(0, 0);   // prologue: 16 vmem in flight

    for (int kt = 0; kt < NKT; ++kt) {
        const int buf = kt & 1;
        if (kt + 1 < NKT) {
            STAGE(buf ^ 1, kt + 1);                      // +16 -> 32 in flight
            asm volatile("s_waitcnt vmcnt(16)" ::: "memory");  // drain tile kt
        } else {
            asm volatile("s_waitcnt vmcnt(0)" ::: "memory");
        }
        __builtin_amdgcn_s_barrier();                    // tile kt visible to all

        const ushortT* tA = &sA[buf][(wr >> 6) * 8192];  // wave's 64-row A tile
        const ushortT* tB = &sB[buf][(wc >> 6) * 8192];  // wave's 64-col B tile
#pragma unroll
        for (int kk = 0; kk < 8; ++kk) {
            int c = kk * 2 + hsel;
            half8 a0 = ldfrag(tA, m0, c);
            half8 a1 = ldfrag(tA, 32 + m0, c);
            half8 b0 = ldfrag(tB, m0, c);
            half8 b1 = ldfrag(tB, 32 + m0, c);
            acc[0][0] = __builtin_amdgcn_mfma_f32_32x32x16_f16(a0, b0, acc[0][0], 0, 0, 0);
            acc[0][1] = __builtin_amdgcn_mfma_f32_32x32x16_f16(a0, b1, acc[0][1], 0, 0, 0);
            acc[1][0] = __builtin_amdgcn_mfma_f32_32x32x16_f16(a1, b0, acc[1][0], 0, 0, 0);
            acc[1][1] = __builtin_amdgcn_mfma_f32_32x32x16_f16(a1, b1, acc[1][1], 0, 0, 0);
        }
        asm volatile("" ::: "memory");                   // keep ds_reads above
        __builtin_amdgcn_s_barrier();                    // reads done before overwrite
    }
#undef STAGE

#pragma unroll
    for (int i = 0; i < 2; ++i)
#pragma unroll
        for (int j = 0; j < 2; ++j) {
            const int gcol = col0 + wc + j * 32 + m0;
            const float mv = mm[gcol];
#pragma unroll
            for (int r = 0; r < 16; ++r) {
                int ri = (r & 3) + 8 * (r >> 2) + 4 * hsel;
                int grow = row0 + wr + i * 32 + ri;
                d2ws[(size_t)grow * N_CLUST + gcol] =
                    yy[grow] - 2.0f * acc[i][j][r] + mv;
            }
        }
}

// ---------------- rescreen: exact argmin per row ----------------
// One wave per row. Scan 1024 screen distances; candidates within MARGIN of
// the row min. 1 candidate -> it's the argmin. Else exact double-acc dots.
__global__ __launch_bounds__(256) void rescreen(
    const float* __restrict__ d2ws, const float* __restrict__ ysrc,
    const float* __restrict__ msrc, const float* __restrict__ yy,
    const float* __restrict__ mm, int* __restrict__ z) {
    const int row = blockIdx.x * 4 + (threadIdx.x >> 6);
    const int l = threadIdx.x & 63;
    const float* dr = d2ws + (size_t)row * N_CLUST;

    float v[16];
#pragma unroll
    for (int k = 0; k < 16; ++k) v[k] = dr[l + 64 * k];

    float mn = v[0];
#pragma unroll
    for (int k = 1; k < 16; ++k) mn = fminf(mn, v[k]);
#pragma unroll
    for (int s = 1; s <= 32; s <<= 1) mn = fminf(mn, __shfl_xor(mn, s, 64));
    const float thr = mn + MARGIN;

    int cnt = 0;
#pragma unroll
    for (int k = 0; k < 16; ++k) cnt += (v[k] <= thr) ? 1 : 0;
#pragma unroll
    for (int s = 1; s <= 32; s <<= 1) cnt += __shfl_xor(cnt, s, 64);

    int zj;
    if (cnt == 1) {
        int cj = 0x7FFFFFFF;
#pragma unroll
        for (int k = 0; k < 16; ++k)
            if (v[k] <= thr) cj = min(cj, l + 64 * k);
#pragma unroll
        for (int s = 1; s <= 32; s <<= 1) cj = min(cj, __shfl_xor(cj, s, 64));
        zj = cj;
    } else {
        double bestd = 1e300;
        int bestj = -1;
        const float4* yp = (const float4*)(ysrc + (size_t)row * KDIM);
        for (int k = 0; k < 16; ++k) {
            unsigned long long mask = __ballot(v[k] <= thr);
            while (mask) {
                int lb = __ffsll((unsigned long long)mask) - 1;
                mask &= mask - 1;
                int j = 64 * k + lb;
                const float4* mp = (const float4*)(msrc + (size_t)j * KDIM);
                double acc = 0.0;
#pragma unroll
                for (int tt = 0; tt < 16; ++tt) {
                    float4 a = yp[l + 64 * tt];
                    float4 b = mp[l + 64 * tt];
                    acc += (double)a.x * b.x + (double)a.y * b.y +
                           (double)a.z * b.z + (double)a.w * b.w;
                }
#pragma unroll
                for (int s = 1; s <= 32; s <<= 1)
                    acc += __shfl_xor(acc, s, 64);
                double d2x = (double)yy[row] - 2.0 * acc + (double)mm[j];
                if (d2x < bestd) { bestd = d2x; bestj = j; }  // strict: low j wins ties
            }
        }
        zj = bestj;
    }
    if (l == 0) z[row] = zj;
}

// ---------------- scatter + output ----------------
__global__ void pick_winner(const int* __restrict__ z,
                            int* __restrict__ winner) {
    int b = blockIdx.x * blockDim.x + threadIdx.x;
    if (b < B_ROWS) atomicMax(&winner[z[b]], b);
}

__global__ __launch_bounds__(256) void write_out(
    const float* __restrict__ y, const float* __restrict__ m,
    const float* __restrict__ sd, const int* __restrict__ winner,
    float* __restrict__ out) {
    const int idx = blockIdx.x;
    const int t = threadIdx.x;
    const int w = winner[idx];
    const float4* mp = (const float4*)(m + (size_t)idx * KDIM);
    const float4* sp = (const float4*)(sd + (size_t)idx * KDIM);
    float4* om = (float4*)(out + (size_t)idx * KDIM);
    float4* os = (float4*)(out + (size_t)(N_CLUST + idx) * KDIM);
    if (w >= 0) {
        const float4* yp = (const float4*)(y + (size_t)w * KDIM);
        for (int i = t; i < KDIM / 4; i += 256) {
            float4 mv = mp[i], yv = yp[i], sv = sp[i];
            float4 nm, ns;
            nm.x = mv.x * EMA_OLD + yv.x * EMA_NEW;
            nm.y = mv.y * EMA_OLD + yv.y * EMA_NEW;
            nm.z = mv.z * EMA_OLD + yv.z * EMA_NEW;
            nm.w = mv.w * EMA_OLD + yv.w * EMA_NEW;
            float dx = nm.x - yv.x, dy = nm.y - yv.y;
            float dz = nm.z - yv.z, dw = nm.w - yv.w;
            ns.x = dx * dx * EMA_OLD + sv.x * EMA_NEW;
            ns.y = dy * dy * EMA_OLD + sv.y * EMA_NEW;
            ns.z = dz * dz * EMA_OLD + sv.z * EMA_NEW;
            ns.w = dw * dw * EMA_OLD + sv.w * EMA_NEW;
            om[i] = nm;
            os[i] = ns;
        }
    } else {
        for (int i = t; i < KDIM / 4; i += 256) {
            om[i] = mp[i];
            os[i] = sp[i];
        }
    }
}

extern "C" void kernel_launch(void* const* d_in, const int* in_sizes, int n_in,
                              void* d_out, int out_size, void* d_ws,
                              size_t ws_size, hipStream_t stream) {
    const float* y  = (const float*)d_in[0];
    const float* m  = (const float*)d_in[1];
    const float* sd = (const float*)d_in[2];
    float* out = (float*)d_out;

    char* ws = (char*)d_ws;
    int* winner = (int*)(ws + WS_WINNER_OFF);
    int* z      = (int*)(ws + WS_Z_OFF);
    float* yy   = (float*)(ws + WS_YY_OFF);
    float* mm   = (float*)(ws + WS_MM_OFF);
    float* d2ws = (float*)(ws + WS_D2_OFF);
    ushortT* yhi = (ushortT*)(ws + WS_YHI_OFF);
    ushortT* mhi = (ushortT*)(ws + WS_MHI_OFF);

    hipMemsetAsync(winner, 0xFF, 4096, stream);   // winner = -1

    convert_sumsq<<<B_ROWS + N_CLUST, 256, 0, stream>>>(y, m, yhi, mhi, yy, mm);

    screen_gemm<<<(B_ROWS / 128) * (N_CLUST / 128), 256, 0, stream>>>(
        yhi, mhi, yy, mm, d2ws);

    rescreen<<<B_ROWS / 4, 256, 0, stream>>>(d2ws, y, m, yy, mm, z);

    pick_winner<<<B_ROWS / 256, 256, 0, stream>>>(z, winner);
    write_out<<<N_CLUST, 256, 0, stream>>>(y, m, sd, winner, out);
}

// Round 2
// 216.302 us; speedup vs baseline: 1.0619x; 1.0619x over previous
//
#include <hip/hip_runtime.h>

#define B_ROWS 4096
#define N_CLUST 1024
#define KDIM 4096
#define NKT 32          // k-tiles of 128 halfs

#define EMA_OLD 0.01f
#define EMA_NEW 0.99f
#define MARGIN 2.0f     // screen d2 error max ~0.27 (40 sigma headroom)

typedef unsigned short ushortT;
typedef _Float16 half8 __attribute__((ext_vector_type(8)));
typedef float f32x16 __attribute__((ext_vector_type(16)));

// ---------------- workspace layout (bytes) ----------------
#define WS_WINNER_OFF 0                  // i32[1024], memset 0xFF
#define WS_Z_OFF      4096               // i32[4096]
#define WS_YY_OFF     20480              // f32[4096]
#define WS_MM_OFF     36864              // f32[1024]
#define WS_D2A_OFF    65536                       // f32[4096*1024] = 16 MiB
#define WS_D2B_OFF    (WS_D2A_OFF + 16777216)     // f32[4096*1024] = 16 MiB
#define WS_YHI_OFF    (WS_D2B_OFF + 16777216)     // 32 MB
#define WS_MHI_OFF    (WS_YHI_OFF + 33554432)     // 8 MB
#define WS_END        (WS_MHI_OFF + 8388608)      // ~74.8 MB

// ---------------- fused f16-hi convert + row sum-of-squares ----------------
// Tiled layout: block (rb, kt) of 64 rows x 128 halfs contiguous (16 KB).
// Within a row (16 chunks of 16B), logical chunk c stored at p = c ^ (r&15).
// One 256-thread block per source row; 512 chunks/row, 2 per thread.
__global__ __launch_bounds__(256) void convert_sumsq(
    const float* __restrict__ ysrc, const float* __restrict__ msrc,
    ushortT* __restrict__ yhi, ushortT* __restrict__ mhi,
    float* __restrict__ yy, float* __restrict__ mm) {
    const int blk = blockIdx.x;
    const float* src;
    ushortT* hi;
    float* out;
    int row;
    if (blk < B_ROWS) {
        src = ysrc; hi = yhi; out = yy + blk; row = blk;
    } else {
        row = blk - B_ROWS;
        src = msrc; hi = mhi; out = mm + row;
    }
    const int r = row & 63, rb = row >> 6;
    const int t = threadIdx.x;
    float s = 0.f;
#pragma unroll
    for (int h = 0; h < 2; ++h) {
        int ci = h * 256 + t;        // physical chunk in row [0,512)
        int kt = ci >> 4, p = ci & 15;
        int c = p ^ (r & 15);
        const float* sp = src + ((size_t)row << 12) + kt * 128 + c * 8;
        float4 v0 = *(const float4*)sp;
        float4 v1 = *(const float4*)(sp + 4);
        float vv[8] = {v0.x, v0.y, v0.z, v0.w, v1.x, v1.y, v1.z, v1.w};
        half8 hv;
#pragma unroll
        for (int i = 0; i < 8; ++i) {
            hv[i] = (_Float16)vv[i];
            s += vv[i] * vv[i];
        }
        size_t off = (((size_t)rb * NKT + kt) * 64 + r) * 128 + p * 8;
        *(half8*)(hi + off) = hv;
    }
    for (int off = 32; off > 0; off >>= 1) s += __shfl_down(s, off, 64);
    __shared__ float red[4];
    if ((t & 63) == 0) red[t >> 6] = s;
    __syncthreads();
    if (t == 0) out[0] = red[0] + red[1] + red[2] + red[3];
}

// ---------------- screen GEMM: d2_screen = yy - 2*Yhi@Mhi^T + mm ----------
__device__ __forceinline__ void gload_lds16(const void* g, void* l) {
    __builtin_amdgcn_global_load_lds(
        (const __attribute__((address_space(1))) unsigned int*)g,
        (__attribute__((address_space(3))) unsigned int*)l, 16, 0, 0);
}

__device__ __forceinline__ half8 ldfrag(const ushortT* s, int r, int c) {
    int p = c ^ (r & 15);
    return *(const half8*)(s + r * 128 + p * 8);
}

// v3: split-K x2. 128x128 block tile, 4 waves each owning 64x64 (2x2 MFMA
// tiles, 1 KB LDS per MFMA = half of v1's traffic), BK=128, SINGLE-buffered
// 64 KB LDS -> 2 blocks/CU (2 waves/SIMD): the vmcnt(0) drain at the
// staging barrier is covered by the co-resident block's compute (TLP), the
// mechanism that let v1 reach its own LDS cap at 4 blocks/CU. Grid 512 =
// 32 row-tiles x 8 col-panels (XCD-pinned via blk&7) x 2 K-halves.
// khalf0 writes yy-2*acc+mm to d2a; khalf1 writes -2*acc to d2b; rescreen
// sums. Split changes screen rounding only; any top-2 gap < MARGIN goes to
// the exact fp64 path, so the argmin cannot flip.
__global__ __launch_bounds__(256, 2) void screen_gemm(
    const ushortT* __restrict__ Ah, const ushortT* __restrict__ Bh,
    const float* __restrict__ yy, const float* __restrict__ mm,
    float* __restrict__ d2a, float* __restrict__ d2b) {
    __shared__ __align__(16) ushortT sA[128 * 128];   // 32 KB
    __shared__ __align__(16) ushortT sB[128 * 128];   // 32 KB

    const int t = threadIdx.x, w = t >> 6, l = t & 63;
    const int by = blockIdx.x & 7;            // col panel -> XCD pinned
    const int kh = (blockIdx.x >> 3) & 1;     // K half
    const int bx = blockIdx.x >> 4;           // row tile 0..31
    const int row0 = bx * 128, col0 = by * 128;
    const int wr = (w >> 1) * 64, wc = (w & 1) * 64;   // wave 64x64 tile
    const int m0 = l & 31, hsel = l >> 5;

    const char* gAbase = (const char*)Ah + (size_t)l * 16;
    const char* gBbase = (const char*)Bh + (size_t)l * 16;

    f32x16 acc[2][2];
#pragma unroll
    for (int i = 0; i < 2; ++i)
#pragma unroll
        for (int j = 0; j < 2; ++j)
#pragma unroll
            for (int r = 0; r < 16; ++r) acc[i][j][r] = 0.f;

    const int kt0 = kh * (NKT / 2);
    for (int ktt = 0; ktt < NKT / 2; ++ktt) {
        const int kt = kt0 + ktt;
        __syncthreads();   // all waves done reading LDS from previous kt
        // stage 64 KB: 32 chunks A + 32 chunks B of 1 KB; 16 per wave
#pragma unroll
        for (int j = 0; j < 8; ++j) {
            int ch = w * 8 + j;
            int tile = ch >> 4, seg = ch & 15;
            size_t go = ((size_t)((2 * bx + tile) * NKT + kt) << 14) +
                        seg * 1024;
            gload_lds16(gAbase + go, (char*)sA + tile * 16384 + seg * 1024);
            size_t gob = ((size_t)((2 * by + tile) * NKT + kt) << 14) +
                         seg * 1024;
            gload_lds16(gBbase + gob, (char*)sB + tile * 16384 + seg * 1024);
        }
        __syncthreads();   // implicit vmcnt(0): staged tile visible

        const ushortT* tA = sA + (wr >> 6) * 8192;   // wave's 64-row A tile
        const ushortT* tB = sB + (wc >> 6) * 8192;   // wave's 64-col B tile
#pragma unroll
        for (int kk = 0; kk < 8; ++kk) {
            int c = kk * 2 + hsel;
            half8 a0 = ldfrag(tA, m0, c);
            half8 a1 = ldfrag(tA, 32 + m0, c);
            half8 b0 = ldfrag(tB, m0, c);
            half8 b1 = ldfrag(tB, 32 + m0, c);
            acc[0][0] = __builtin_amdgcn_mfma_f32_32x32x16_f16(a0, b0, acc[0][0], 0, 0, 0);
            acc[0][1] = __builtin_amdgcn_mfma_f32_32x32x16_f16(a0, b1, acc[0][1], 0, 0, 0);
            acc[1][0] = __builtin_amdgcn_mfma_f32_32x32x16_f16(a1, b0, acc[1][0], 0, 0, 0);
            acc[1][1] = __builtin_amdgcn_mfma_f32_32x32x16_f16(a1, b1, acc[1][1], 0, 0, 0);
        }
    }

    if (kh == 0) {
#pragma unroll
        for (int i = 0; i < 2; ++i)
#pragma unroll
            for (int j = 0; j < 2; ++j) {
                const int gcol = col0 + wc + j * 32 + m0;
                const float mv = mm[gcol];
#pragma unroll
                for (int r = 0; r < 16; ++r) {
                    int ri = (r & 3) + 8 * (r >> 2) + 4 * hsel;
                    int grow = row0 + wr + i * 32 + ri;
                    d2a[(size_t)grow * N_CLUST + gcol] =
                        yy[grow] - 2.0f * acc[i][j][r] + mv;
                }
            }
    } else {
#pragma unroll
        for (int i = 0; i < 2; ++i)
#pragma unroll
            for (int j = 0; j < 2; ++j) {
                const int gcol = col0 + wc + j * 32 + m0;
#pragma unroll
                for (int r = 0; r < 16; ++r) {
                    int ri = (r & 3) + 8 * (r >> 2) + 4 * hsel;
                    int grow = row0 + wr + i * 32 + ri;
                    d2b[(size_t)grow * N_CLUST + gcol] = -2.0f * acc[i][j][r];
                }
            }
    }
}

// ---------------- rescreen: exact argmin per row ----------------
// One wave per row. Screen d2 = d2a + d2b (split-K partials). Candidates
// within MARGIN of the row min. 1 candidate -> it's the argmin. Else exact
// double-acc dots.
__global__ __launch_bounds__(256) void rescreen(
    const float* __restrict__ d2a, const float* __restrict__ d2b,
    const float* __restrict__ ysrc, const float* __restrict__ msrc,
    const float* __restrict__ yy, const float* __restrict__ mm,
    int* __restrict__ z) {
    const int row = blockIdx.x * 4 + (threadIdx.x >> 6);
    const int l = threadIdx.x & 63;
    const float* dra = d2a + (size_t)row * N_CLUST;
    const float* drb = d2b + (size_t)row * N_CLUST;

    float v[16];
#pragma unroll
    for (int k = 0; k < 16; ++k) v[k] = dra[l + 64 * k] + drb[l + 64 * k];

    float mn = v[0];
#pragma unroll
    for (int k = 1; k < 16; ++k) mn = fminf(mn, v[k]);
#pragma unroll
    for (int s = 1; s <= 32; s <<= 1) mn = fminf(mn, __shfl_xor(mn, s, 64));
    const float thr = mn + MARGIN;

    int cnt = 0;
#pragma unroll
    for (int k = 0; k < 16; ++k) cnt += (v[k] <= thr) ? 1 : 0;
#pragma unroll
    for (int s = 1; s <= 32; s <<= 1) cnt += __shfl_xor(cnt, s, 64);

    int zj;
    if (cnt == 1) {
        int cj = 0x7FFFFFFF;
#pragma unroll
        for (int k = 0; k < 16; ++k)
            if (v[k] <= thr) cj = min(cj, l + 64 * k);
#pragma unroll
        for (int s = 1; s <= 32; s <<= 1) cj = min(cj, __shfl_xor(cj, s, 64));
        zj = cj;
    } else {
        double bestd = 1e300;
        int bestj = -1;
        const float4* yp = (const float4*)(ysrc + (size_t)row * KDIM);
        for (int k = 0; k < 16; ++k) {
            unsigned long long mask = __ballot(v[k] <= thr);
            while (mask) {
                int lb = __ffsll((unsigned long long)mask) - 1;
                mask &= mask - 1;
                int j = 64 * k + lb;
                const float4* mp = (const float4*)(msrc + (size_t)j * KDIM);
                double acc = 0.0;
#pragma unroll
                for (int tt = 0; tt < 16; ++tt) {
                    float4 a = yp[l + 64 * tt];
                    float4 b = mp[l + 64 * tt];
                    acc += (double)a.x * b.x + (double)a.y * b.y +
                           (double)a.z * b.z + (double)a.w * b.w;
                }
#pragma unroll
                for (int s = 1; s <= 32; s <<= 1)
                    acc += __shfl_xor(acc, s, 64);
                double d2x = (double)yy[row] - 2.0 * acc + (double)mm[j];
                if (d2x < bestd) { bestd = d2x; bestj = j; }  // strict: low j wins ties
            }
        }
        zj = bestj;
    }
    if (l == 0) z[row] = zj;
}

// ---------------- scatter + output ----------------
__global__ void pick_winner(const int* __restrict__ z,
                            int* __restrict__ winner) {
    int b = blockIdx.x * blockDim.x + threadIdx.x;
    if (b < B_ROWS) atomicMax(&winner[z[b]], b);
}

__global__ __launch_bounds__(256) void write_out(
    const float* __restrict__ y, const float* __restrict__ m,
    const float* __restrict__ sd, const int* __restrict__ winner,
    float* __restrict__ out) {
    const int idx = blockIdx.x;
    const int t = threadIdx.x;
    const int w = winner[idx];
    const float4* mp = (const float4*)(m + (size_t)idx * KDIM);
    const float4* sp = (const float4*)(sd + (size_t)idx * KDIM);
    float4* om = (float4*)(out + (size_t)idx * KDIM);
    float4* os = (float4*)(out + (size_t)(N_CLUST + idx) * KDIM);
    if (w >= 0) {
        const float4* yp = (const float4*)(y + (size_t)w * KDIM);
        for (int i = t; i < KDIM / 4; i += 256) {
            float4 mv = mp[i], yv = yp[i], sv = sp[i];
            float4 nm, ns;
            nm.x = mv.x * EMA_OLD + yv.x * EMA_NEW;
            nm.y = mv.y * EMA_OLD + yv.y * EMA_NEW;
            nm.z = mv.z * EMA_OLD + yv.z * EMA_NEW;
            nm.w = mv.w * EMA_OLD + yv.w * EMA_NEW;
            float dx = nm.x - yv.x, dy = nm.y - yv.y;
            float dz = nm.z - yv.z, dw = nm.w - yv.w;
            ns.x = dx * dx * EMA_OLD + sv.x * EMA_NEW;
            ns.y = dy * dy * EMA_OLD + sv.y * EMA_NEW;
            ns.z = dz * dz * EMA_OLD + sv.z * EMA_NEW;
            ns.w = dw * dw * EMA_OLD + sv.w * EMA_NEW;
            om[i] = nm;
            os[i] = ns;
        }
    } else {
        for (int i = t; i < KDIM / 4; i += 256) {
            om[i] = mp[i];
            os[i] = sp[i];
        }
    }
}

extern "C" void kernel_launch(void* const* d_in, const int* in_sizes, int n_in,
                              void* d_out, int out_size, void* d_ws,
                              size_t ws_size, hipStream_t stream) {
    const float* y  = (const float*)d_in[0];
    const float* m  = (const float*)d_in[1];
    const float* sd = (const float*)d_in[2];
    float* out = (float*)d_out;

    char* ws = (char*)d_ws;
    int* winner = (int*)(ws + WS_WINNER_OFF);
    int* z      = (int*)(ws + WS_Z_OFF);
    float* yy   = (float*)(ws + WS_YY_OFF);
    float* mm   = (float*)(ws + WS_MM_OFF);
    float* d2a  = (float*)(ws + WS_D2A_OFF);
    float* d2b  = (float*)(ws + WS_D2B_OFF);
    ushortT* yhi = (ushortT*)(ws + WS_YHI_OFF);
    ushortT* mhi = (ushortT*)(ws + WS_MHI_OFF);

    hipMemsetAsync(winner, 0xFF, 4096, stream);   // winner = -1

    convert_sumsq<<<B_ROWS + N_CLUST, 256, 0, stream>>>(y, m, yhi, mhi, yy, mm);

    screen_gemm<<<(B_ROWS / 128) * (N_CLUST / 128) * 2, 256, 0, stream>>>(
        yhi, mhi, yy, mm, d2a, d2b);

    rescreen<<<B_ROWS / 4, 256, 0, stream>>>(d2a, d2b, y, m, yy, mm, z);

    pick_winner<<<B_ROWS / 256, 256, 0, stream>>>(z, winner);
    write_out<<<N_CLUST, 256, 0, stream>>>(y, m, sd, winner, out);
}